// Round 7
// baseline (263.294 us; speedup 1.0000x reference)
//
#include <hip/hip_runtime.h>

#define N_DIM 4096
#define NE    16            // n split 16 ways -> 256 cols/block, 4 chunks of 64

typedef float f4  __attribute__((ext_vector_type(4)));
typedef short s8v __attribute__((ext_vector_type(8)));

#if defined(__has_builtin)
#if __has_builtin(__builtin_amdgcn_cvt_pk_bf16_f32)
#define HAVE_CVT_PK 1
#endif
#endif

static __device__ __forceinline__ unsigned int f2bf_pair(float lo, float hi) {
#ifdef HAVE_CVT_PK
    typedef __bf16 bf2 __attribute__((ext_vector_type(2)));
    bf2 p = __builtin_amdgcn_cvt_pk_bf16_f32(lo, hi);
    return __builtin_bit_cast(unsigned int, p);
#else
    unsigned int ul = __builtin_bit_cast(unsigned int, lo);
    unsigned int uh = __builtin_bit_cast(unsigned int, hi);
    ul = ul + 0x7fffu + ((ul >> 16) & 1u);
    uh = uh + 0x7fffu + ((uh >> 16) & 1u);
    return (uh & 0xffff0000u) | (ul >> 16);
#endif
}

static __device__ __forceinline__ s8v cvt8(f4 a, f4 b) {
    unsigned int u4[4] = { f2bf_pair(a[0], a[1]), f2bf_pair(a[2], a[3]),
                           f2bf_pair(b[0], b[1]), f2bf_pair(b[2], b[3]) };
    return __builtin_bit_cast(s8v, u4);
}

#define MFMA(a, b, c) __builtin_amdgcn_mfma_f32_16x16x32_bf16((a), (b), (c), 0, 0, 0)

// zero out + the 64 per-i-tile ticket counters (ws is re-poisoned 0xAA each launch)
__global__ void zero_kernel(float* __restrict__ out, int* __restrict__ cnt) {
    if (threadIdx.x < 64) cnt[threadIdx.x] = 0;
    if (threadIdx.x == 0) out[0] = 0.f;
}

// Grid (16 ne, 64 it), 256 thr, 4 chunks of 64 cols. R6's proven staging
// (contiguous 32 B/thread loads, conflict-free bijective LDS packets, raw
// lgkm-only barrier) at 4 blocks/CU instead of 2. Last block of each i-tile
// group (ticket) fuses the epilogue: reads the 16 L2-hot partials densely,
// exact-fp32 num/den, one atomic per i-tile.
__global__ __launch_bounds__(256) void gemm_fused_kernel(
    const float* __restrict__ zs, const float* __restrict__ X,
    const float* __restrict__ varp, float* __restrict__ part,
    int* __restrict__ cnt, float* __restrict__ out) {
    __shared__ s8v zsP[2][512];   // 64 k x 64 n bf16, dbuf (16 KB)
    __shared__ s8v xP [2][512];   // 64 i x 64 n bf16, dbuf (16 KB)

    const int tid  = threadIdx.x;
    const int lane = tid & 63;
    const int w    = tid >> 6;
    const int n0   = blockIdx.x * 256;
    const int i0   = blockIdx.y * 64;

    const int r0  = tid >> 3;
    const int cid = (tid & 7) * 8;
    const int stp = (tid >> 2) & 1;
    const int csb = tid & 3;
    const int g0  = (((r0 >> 4) * 2 + stp) << 6) | (r0 & 15) | (csb << 4);
    const int g1  = ((((r0 + 32) >> 4) * 2 + stp) << 6) | (r0 & 15) | (csb << 4);

    const float* gz0 = zs + (size_t)r0 * N_DIM + n0 + cid;
    const float* gz1 = zs + (size_t)(r0 + 32) * N_DIM + n0 + cid;
    const float* gx0 = X  + (size_t)(i0 + r0) * N_DIM + n0 + cid;
    const float* gx1 = X  + (size_t)(i0 + r0 + 32) * N_DIM + n0 + cid;

    f4 rz[4], rx[4];
    rz[0] = *(const f4*)(gz0);     rz[1] = *(const f4*)(gz0 + 4);
    rz[2] = *(const f4*)(gz1);     rz[3] = *(const f4*)(gz1 + 4);
    rx[0] = *(const f4*)(gx0);     rx[1] = *(const f4*)(gx0 + 4);
    rx[2] = *(const f4*)(gx1);     rx[3] = *(const f4*)(gx1 + 4);

    f4 acc[2][2] = {};
    const int kh = (w & 1) * 2;
    const int ih = (w >> 1) * 2;

    for (int c = 0; c < 4; ++c) {
        const int buf = c & 1;
        s8v pz0 = cvt8(rz[0], rz[1]);
        s8v pz1 = cvt8(rz[2], rz[3]);
        s8v px0 = cvt8(rx[0], rx[1]);
        s8v px1 = cvt8(rx[2], rx[3]);
        if (c < 3) {
            const int off = (c + 1) * 64;
            rz[0] = *(const f4*)(gz0 + off); rz[1] = *(const f4*)(gz0 + off + 4);
            rz[2] = *(const f4*)(gz1 + off); rz[3] = *(const f4*)(gz1 + off + 4);
            rx[0] = *(const f4*)(gx0 + off); rx[1] = *(const f4*)(gx0 + off + 4);
            rx[2] = *(const f4*)(gx1 + off); rx[3] = *(const f4*)(gx1 + off + 4);
        }
        zsP[buf][g0] = pz0;  zsP[buf][g1] = pz1;
        xP[buf][g0]  = px0;  xP[buf][g1]  = px1;
        asm volatile("s_waitcnt lgkmcnt(0)\n\ts_barrier" ::: "memory");

        s8v a0s0 = zsP[buf][((kh    ) * 2 + 0) * 64 + lane];
        s8v a0s1 = zsP[buf][((kh    ) * 2 + 1) * 64 + lane];
        s8v a1s0 = zsP[buf][((kh + 1) * 2 + 0) * 64 + lane];
        s8v a1s1 = zsP[buf][((kh + 1) * 2 + 1) * 64 + lane];
        s8v b0s0 = xP [buf][((ih    ) * 2 + 0) * 64 + lane];
        s8v b0s1 = xP [buf][((ih    ) * 2 + 1) * 64 + lane];
        s8v b1s0 = xP [buf][((ih + 1) * 2 + 0) * 64 + lane];
        s8v b1s1 = xP [buf][((ih + 1) * 2 + 1) * 64 + lane];

        acc[0][0] = MFMA(a0s0, b0s0, acc[0][0]);
        acc[0][1] = MFMA(a0s0, b1s0, acc[0][1]);
        acc[1][0] = MFMA(a1s0, b0s0, acc[1][0]);
        acc[1][1] = MFMA(a1s0, b1s0, acc[1][1]);
        acc[0][0] = MFMA(a0s1, b0s1, acc[0][0]);
        acc[0][1] = MFMA(a0s1, b1s1, acc[0][1]);
        acc[1][0] = MFMA(a1s1, b0s1, acc[1][0]);
        acc[1][1] = MFMA(a1s1, b1s1, acc[1][1]);
    }

    // partial store: [it][ne][j], j = (ktile*4 + itile)*64 + lane — consumer-dense
    f4* pp = (f4*)part;
    const int tb = (blockIdx.y * NE + blockIdx.x) * 1024;
    #pragma unroll
    for (int a = 0; a < 2; ++a)
        #pragma unroll
        for (int b = 0; b < 2; ++b)
            pp[tb + ((kh + a) * 4 + (ih + b)) * 64 + lane] = acc[a][b];

    // ticket: last block of this i-tile group fuses the epilogue
    __threadfence();
    __shared__ int lastf;
    if (tid == 0) lastf = (atomicAdd(&cnt[blockIdx.y], 1) == NE - 1);
    __syncthreads();
    if (!lastf) return;
    __threadfence();   // acquire: other producers' partials now visible

    // thread t sums j = 4t..4t+3 over the 16 ne partials (64 B/lane dense reads)
    f4 s[4] = {};
    for (int ne = 0; ne < NE; ++ne) {
        const f4* q = pp + (blockIdx.y * NE + ne) * 1024 + tid * 4;
        #pragma unroll
        for (int jj = 0; jj < 4; ++jj) s[jj] += q[jj];
    }
    // decode: j0=4t -> ktile=j0>>8, itile=(j0>>6)&3, lanes j0&63..+3 (same lane>>4)
    const int j0  = tid * 4;
    const int kt  = j0 >> 8;
    const int itl = (j0 >> 6) & 3;
    const int ln0 = j0 & 63;
    const int k0  = kt * 16 + (ln0 >> 4) * 4;          // C/D: row=(lane>>4)*4+r
    const int ib  = blockIdx.y * 64 + itl * 16 + (ln0 & 15);
    const float var = varp[0];

    float vsum = 0.f;
    #pragma unroll
    for (int c2 = 0; c2 < 4; ++c2) {
        const int   i  = ib + c2;                       // lane = ln0+c2 -> col i
        const float dg = X[(size_t)i * (N_DIM + 1)];
        #pragma unroll
        for (int r = 0; r < 4; ++r) {
            float num = zs[(size_t)(k0 + r) * N_DIM + i] * dg;   // exact fp32
            float den = s[c2][r] - num;
            vsum += num / (var + den);
        }
    }
    #pragma unroll
    for (int off = 32; off >= 1; off >>= 1) vsum += __shfl_down(vsum, off);
    __shared__ float wsum[4];
    if (lane == 0) wsum[w] = vsum;
    __syncthreads();
    if (tid == 0)
        atomicAdd(out, -(wsum[0] + wsum[1] + wsum[2] + wsum[3]) * (1.0f / 64.0f));
}

extern "C" void kernel_launch(void* const* d_in, const int* in_sizes, int n_in,
                              void* d_out, int out_size, void* d_ws, size_t ws_size,
                              hipStream_t stream) {
    const float* zs   = (const float*)d_in[0];
    const float* X    = (const float*)d_in[1];
    const float* varp = (const float*)d_in[2];
    float* out  = (float*)d_out;
    float* part = (float*)d_ws;                       // 64 it x 16 ne x 16 KB = 16 MB
    int*   cnt  = (int*)((char*)d_ws + (size_t)64 * NE * 1024 * 16);

    hipLaunchKernelGGL(zero_kernel, dim3(1), dim3(64), 0, stream, out, cnt);
    hipLaunchKernelGGL(gemm_fused_kernel, dim3(NE, 64), dim3(256), 0, stream,
                       zs, X, varp, part, cnt, out);
}

// Round 8
// 109.783 us; speedup vs baseline: 2.3983x; 2.3983x over previous
//
#include <hip/hip_runtime.h>

#define N_DIM 4096
#define NE    16            // n split 16 ways -> 256 cols/block, 4 chunks of 64

typedef float f4  __attribute__((ext_vector_type(4)));
typedef short s8v __attribute__((ext_vector_type(8)));

#if defined(__has_builtin)
#if __has_builtin(__builtin_amdgcn_cvt_pk_bf16_f32)
#define HAVE_CVT_PK 1
#endif
#endif

static __device__ __forceinline__ unsigned int f2bf_pair(float lo, float hi) {
#ifdef HAVE_CVT_PK
    typedef __bf16 bf2 __attribute__((ext_vector_type(2)));
    bf2 p = __builtin_amdgcn_cvt_pk_bf16_f32(lo, hi);
    return __builtin_bit_cast(unsigned int, p);
#else
    unsigned int ul = __builtin_bit_cast(unsigned int, lo);
    unsigned int uh = __builtin_bit_cast(unsigned int, hi);
    ul = ul + 0x7fffu + ((ul >> 16) & 1u);
    uh = uh + 0x7fffu + ((uh >> 16) & 1u);
    return (uh & 0xffff0000u) | (ul >> 16);
#endif
}

static __device__ __forceinline__ s8v cvt8(f4 a, f4 b) {
    unsigned int u4[4] = { f2bf_pair(a[0], a[1]), f2bf_pair(a[2], a[3]),
                           f2bf_pair(b[0], b[1]), f2bf_pair(b[2], b[3]) };
    return __builtin_bit_cast(s8v, u4);
}

#define MFMA(a, b, c) __builtin_amdgcn_mfma_f32_16x16x32_bf16((a), (b), (c), 0, 0, 0)

__global__ void zero_out_kernel(float* __restrict__ out) {
    if (threadIdx.x == 0 && blockIdx.x == 0) out[0] = 0.f;
}

// Grid (16 ne, 64 it), 256 thr, 4 chunks of 64 cols, 4 blocks/CU.
// LDS granule (16 B = 8 bf16) for chunk element (row, c8=col/8) lives at
//   g = row*8 + (c8 ^ (row&7))               [XOR swizzle]
// WRITE:  thread (r0=tid>>3, c8w=tid&7): g&7 = c8w^(r0&7) — each 8-lane phase
//         covers all 8 bank groups (R6/R7's layout put 8 lanes on ONE group:
//         3.67M conflict cycles).
// READ:   lane l, tile (kt,s): g = kt*128 + (l&15)*8 + ((s*4+(l>>4))^(l&7))
//         — every phase again covers all 8 groups. Conflict-free both ways.
// Raw lgkm-only barrier (no vmcnt drain) per chunk; NO fences/tickets (R7's
// __threadfence pair serialized the whole memory system -> 200 us).
__global__ __launch_bounds__(256) void gemm_part_kernel(
    const float* __restrict__ zs, const float* __restrict__ X,
    float* __restrict__ part) {
    __shared__ s8v zsP[2][512];   // 64 k x 64 n bf16, dbuf (16 KB)
    __shared__ s8v xP [2][512];   // 64 i x 64 n bf16, dbuf (16 KB)

    const int tid  = threadIdx.x;
    const int lane = tid & 63;
    const int w    = tid >> 6;
    const int n0   = blockIdx.x * 256;
    const int i0   = blockIdx.y * 64;

    // staging: thread covers rows r0, r0+32, cols c8w*8..+8 (contiguous 256 B
    // per 8-thread row-group in global)
    const int r0  = tid >> 3;
    const int c8w = tid & 7;
    const int g0  = r0 * 8 + (c8w ^ (r0 & 7));
    const int g1  = g0 + 256;                  // row r0+32: (r0+32)&7 == r0&7

    const float* gz0 = zs + (size_t)r0 * N_DIM + n0 + c8w * 8;
    const float* gz1 = gz0 + (size_t)32 * N_DIM;
    const float* gx0 = X  + (size_t)(i0 + r0) * N_DIM + n0 + c8w * 8;
    const float* gx1 = gx0 + (size_t)32 * N_DIM;

    f4 rz[4], rx[4];
    rz[0] = *(const f4*)(gz0);     rz[1] = *(const f4*)(gz0 + 4);
    rz[2] = *(const f4*)(gz1);     rz[3] = *(const f4*)(gz1 + 4);
    rx[0] = *(const f4*)(gx0);     rx[1] = *(const f4*)(gx0 + 4);
    rx[2] = *(const f4*)(gx1);     rx[3] = *(const f4*)(gx1 + 4);

    f4 acc[2][2] = {};
    const int kh = (w & 1) * 2;          // wave's k-tiles {kh, kh+1}
    const int ih = (w >> 1) * 2;         // wave's i-tiles {ih, ih+1}
    const int u0 = (lane & 15) * 8;
    const int xs0 = (lane >> 4) ^ (lane & 7);   // swizzle term, step 0
    const int xs1 = xs0 ^ 4;                    // step 1

    for (int c = 0; c < 4; ++c) {
        const int buf = c & 1;
        s8v pz0 = cvt8(rz[0], rz[1]);
        s8v pz1 = cvt8(rz[2], rz[3]);
        s8v px0 = cvt8(rx[0], rx[1]);
        s8v px1 = cvt8(rx[2], rx[3]);
        if (c < 3) {   // next chunk's loads stay in flight across s_barrier
            const int off = (c + 1) * 64;
            rz[0] = *(const f4*)(gz0 + off); rz[1] = *(const f4*)(gz0 + off + 4);
            rz[2] = *(const f4*)(gz1 + off); rz[3] = *(const f4*)(gz1 + off + 4);
            rx[0] = *(const f4*)(gx0 + off); rx[1] = *(const f4*)(gx0 + off + 4);
            rx[2] = *(const f4*)(gx1 + off); rx[3] = *(const f4*)(gx1 + off + 4);
        }
        zsP[buf][g0] = pz0;  zsP[buf][g1] = pz1;
        xP[buf][g0]  = px0;  xP[buf][g1]  = px1;
        asm volatile("s_waitcnt lgkmcnt(0)\n\ts_barrier" ::: "memory");

        s8v a0s0 = zsP[buf][(kh    ) * 128 + u0 + xs0];
        s8v a0s1 = zsP[buf][(kh    ) * 128 + u0 + xs1];
        s8v a1s0 = zsP[buf][(kh + 1) * 128 + u0 + xs0];
        s8v a1s1 = zsP[buf][(kh + 1) * 128 + u0 + xs1];
        s8v b0s0 = xP [buf][(ih    ) * 128 + u0 + xs0];
        s8v b0s1 = xP [buf][(ih    ) * 128 + u0 + xs1];
        s8v b1s0 = xP [buf][(ih + 1) * 128 + u0 + xs0];
        s8v b1s1 = xP [buf][(ih + 1) * 128 + u0 + xs1];

        acc[0][0] = MFMA(a0s0, b0s0, acc[0][0]);
        acc[0][1] = MFMA(a0s0, b1s0, acc[0][1]);
        acc[1][0] = MFMA(a1s0, b0s0, acc[1][0]);
        acc[1][1] = MFMA(a1s0, b1s0, acc[1][1]);
        acc[0][0] = MFMA(a0s1, b0s1, acc[0][0]);
        acc[0][1] = MFMA(a0s1, b1s1, acc[0][1]);
        acc[1][0] = MFMA(a1s1, b0s1, acc[1][0]);
        acc[1][1] = MFMA(a1s1, b1s1, acc[1][1]);
    }

    // partial store: [it][ne][j], j = (ktile*4 + itile)*64 + lane — consumer-dense
    f4* pp = (f4*)part;
    const int tb = (blockIdx.y * NE + blockIdx.x) * 1024;
    #pragma unroll
    for (int a = 0; a < 2; ++a)
        #pragma unroll
        for (int b = 0; b < 2; ++b)
            pp[tb + ((kh + a) * 4 + (ih + b)) * 64 + lane] = acc[a][b];
}

// Separate epilogue (stream-ordered, no fences): one block per i-tile group.
// Thread t sums granules j=4t..4t+3 over the 16 ne partials (64 B/lane dense),
// exact-fp32 num/den, one atomic per block. (Consumer logic verified in R7.)
__global__ __launch_bounds__(256) void epilogue_kernel(
    const float* __restrict__ part, const float* __restrict__ zs,
    const float* __restrict__ X, const float* __restrict__ varp,
    float* __restrict__ out) {
    const int tid  = threadIdx.x;
    const int lane = tid & 63;
    const int w    = tid >> 6;
    const int ib   = blockIdx.x;
    const f4* pp   = (const f4*)part;

    f4 s[4] = {};
    for (int ne = 0; ne < NE; ++ne) {
        const f4* q = pp + (ib * NE + ne) * 1024 + tid * 4;
        #pragma unroll
        for (int jj = 0; jj < 4; ++jj) s[jj] += q[jj];
    }
    const int j0  = tid * 4;
    const int kt  = j0 >> 8;
    const int itl = (j0 >> 6) & 3;
    const int ln0 = j0 & 63;
    const int k0  = kt * 16 + (ln0 >> 4) * 4;      // C/D: row=(lane>>4)*4+r
    const int ibs = ib * 64 + itl * 16 + (ln0 & 15);
    const float var = varp[0];

    float vsum = 0.f;
    #pragma unroll
    for (int c2 = 0; c2 < 4; ++c2) {
        const int   i  = ibs + c2;                  // lane ln0+c2 -> col i
        const float dg = X[(size_t)i * (N_DIM + 1)];
        #pragma unroll
        for (int r = 0; r < 4; ++r) {
            float num = zs[(size_t)(k0 + r) * N_DIM + i] * dg;   // exact fp32
            float den = s[c2][r] - num;
            vsum += num / (var + den);
        }
    }
    #pragma unroll
    for (int off = 32; off >= 1; off >>= 1) vsum += __shfl_down(vsum, off);
    __shared__ float wsum[4];
    if (lane == 0) wsum[w] = vsum;
    __syncthreads();
    if (tid == 0)
        atomicAdd(out, -(wsum[0] + wsum[1] + wsum[2] + wsum[3]) * (1.0f / 64.0f));
}

extern "C" void kernel_launch(void* const* d_in, const int* in_sizes, int n_in,
                              void* d_out, int out_size, void* d_ws, size_t ws_size,
                              hipStream_t stream) {
    const float* zs   = (const float*)d_in[0];
    const float* X    = (const float*)d_in[1];
    const float* varp = (const float*)d_in[2];
    float* out  = (float*)d_out;
    float* part = (float*)d_ws;     // 64 it x 16 ne x 16 KB = 16 MB

    hipLaunchKernelGGL(zero_out_kernel, dim3(1), dim3(64), 0, stream, out);
    hipLaunchKernelGGL(gemm_part_kernel, dim3(NE, 64), dim3(256), 0, stream, zs, X, part);
    hipLaunchKernelGGL(epilogue_kernel, dim3(64), dim3(256), 0, stream,
                       part, zs, X, varp, out);
}